// Round 1
// baseline (786.484 us; speedup 1.0000x reference)
//
#include <hip/hip_runtime.h>
#include <hip/hip_bf16.h>
#include <stdint.h>

// Problem dims (fixed by reference)
#define T_LEN 128
#define B_SZ  256
#define D_IN  1024
#define H_DIM 1024
#define NQ    8
#define VOCAB 32000
#define TAGS  1024

typedef __attribute__((ext_vector_type(8))) short short8;   // 8 bf16 (4 VGPRs)
typedef __attribute__((ext_vector_type(4))) float f32x4;

// ---------- helpers ----------
__device__ __forceinline__ float sigmoid_f(float x) {
    return 1.f / (1.f + __expf(-x));
}
__device__ __forceinline__ float tanh_f(float x) {
    // 1 - 2/(e^{2x}+1); saturates correctly at +/-1 (inf-safe)
    return 1.f - 2.f / (__expf(2.f * x) + 1.f);
}
__device__ __forceinline__ void gload_lds16(void* lds_base, const void* gptr) {
    __builtin_amdgcn_global_load_lds(
        (__attribute__((address_space(1))) const void*)gptr,
        (__attribute__((address_space(3))) void*)lds_base,
        16, 0, 0);
}

// ---------- K0: W_tag (K x N fp32) -> WtT (N x K bf16) ----------
__global__ __launch_bounds__(256) void k_wt_transpose(const float* __restrict__ W,
                                                      __hip_bfloat16* __restrict__ WtT) {
    __shared__ float tile[32][33];
    const int kb = blockIdx.x * 32, nb = blockIdx.y * 32;
    const int r = threadIdx.x >> 5, c = threadIdx.x & 31;
#pragma unroll
    for (int i = 0; i < 4; ++i)
        tile[r + 8 * i][c] = W[(size_t)(kb + r + 8 * i) * TAGS + nb + c];
    __syncthreads();
#pragma unroll
    for (int i = 0; i < 4; ++i)
        WtT[(size_t)(nb + r + 8 * i) * H_DIM + kb + c] = __float2bfloat16(tile[c][r + 8 * i]);
}

// ---------- K1: gx[r][o] = emb[sent[r]] . Wg_x[:,o] + bg[o] + theta[o] ----------
// r = t*B + b (row-major over (T,B)); o = g*8+q over the 32 gate pre-activations.
// The x-contribution of the QLSTM gate einsum is time-independent -> hoisted here.
// wave wv owns outputs {2wv, 2wv+1}; lane covers c = j*256 + lane*4 + e (conflict-free
// full-spread LDS reads); 6-level shfl_xor butterfly; no LDS reduction array.
#define GX_ROWS 128
__global__ __launch_bounds__(1024) void k_gx(
    const int* __restrict__ sent, const float* __restrict__ emb,
    const float* __restrict__ Wg, const float* __restrict__ bg,
    const float* __restrict__ theta, float* __restrict__ gx)
{
    __shared__ float xs[2][1024];
    const int tid = threadIdx.x, lane = tid & 63, wv = tid >> 6;
    const int o0 = 2 * wv, o1 = o0 + 1;
    const int g0 = o0 >> 3, q0 = o0 & 7;
    const int g1 = o1 >> 3, q1 = o1 & 7;

    float wA[16], wB[16];
#pragma unroll
    for (int j = 0; j < 4; ++j)
#pragma unroll
        for (int e = 0; e < 4; ++e) {
            const int c = j * 256 + lane * 4 + e;            // x part: rows [0,1024)
            wA[4 * j + e] = Wg[((size_t)g0 * 2048 + c) * 8 + q0];
            wB[4 * j + e] = Wg[((size_t)g1 * 2048 + c) * 8 + q1];
        }
    const float bt0 = bg[o0] + theta[o0];
    const float bt1 = bg[o1] + theta[o1];

    const int r0 = blockIdx.x * GX_ROWS;
    xs[0][tid] = emb[(size_t)sent[r0] * D_IN + tid];
    __syncthreads();

    int cur = 0;
    for (int i = 0; i < GX_ROWS; ++i) {
        const int rn = r0 + ((i + 1 < GX_ROWS) ? (i + 1) : i);
        const float xnext = emb[(size_t)sent[rn] * D_IN + tid];   // prefetch next row

        const float4* x4 = (const float4*)xs[cur];
        float a0 = 0.f, a1 = 0.f;
#pragma unroll
        for (int j = 0; j < 4; ++j) {
            float4 v = x4[j * 64 + lane];
            a0 = fmaf(wA[4 * j + 0], v.x, a0); a1 = fmaf(wB[4 * j + 0], v.x, a1);
            a0 = fmaf(wA[4 * j + 1], v.y, a0); a1 = fmaf(wB[4 * j + 1], v.y, a1);
            a0 = fmaf(wA[4 * j + 2], v.z, a0); a1 = fmaf(wB[4 * j + 2], v.z, a1);
            a0 = fmaf(wA[4 * j + 3], v.w, a0); a1 = fmaf(wB[4 * j + 3], v.w, a1);
        }
#pragma unroll
        for (int d = 1; d < 64; d <<= 1) {
            a0 += __shfl_xor(a0, d, 64);
            a1 += __shfl_xor(a1, d, 64);
        }
        xs[cur ^ 1][tid] = xnext;      // other buffer: safe before barrier
        if (lane == 0) {
            float2 o2; o2.x = a0 + bt0; o2.y = a1 + bt1;
            *(float2*)&gx[(size_t)(r0 + i) * 32 + o0] = o2;
        }
        __syncthreads();
        cur ^= 1;
    }
}

// ---------- K2: recurrent QLSTM (h-part only). one block per batch element ----------
// Phase 1: wave wv computes raw[2wv],raw[2wv+1] = h_{t-1} . Wg_h (f32 weights in regs,
// butterfly reduce). Phase 2: per-thread projection + gates. 2 barriers/step, no
// global loads in the loop (gx slice staged in LDS once).
__global__ __launch_bounds__(1024) void k_qlstm(
    const float* __restrict__ gx, const float* __restrict__ Wg,
    const float* __restrict__ Wp, const float* __restrict__ bp,
    __hip_bfloat16* __restrict__ hb)
{
    __shared__ float hs[1024];
    __shared__ float qs[32];
    __shared__ float gxl[T_LEN * 32];          // 16 KB: this block's gx slice

    const int tid = threadIdx.x, lane = tid & 63, wv = tid >> 6;
    const int b = blockIdx.x;
    const int o0 = 2 * wv, o1 = o0 + 1;
    const int g0 = o0 >> 3, q0 = o0 & 7;
    const int g1 = o1 >> 3, q1 = o1 & 7;

    // phase-1 weights: h part of Wg (rows 1024..2047), f32 (no unpack in loop)
    float wA[16], wB[16];
#pragma unroll
    for (int j = 0; j < 4; ++j)
#pragma unroll
        for (int e = 0; e < 4; ++e) {
            const int c = j * 256 + lane * 4 + e;
            wA[4 * j + e] = Wg[((size_t)g0 * 2048 + 1024 + c) * 8 + q0];
            wB[4 * j + e] = Wg[((size_t)g1 * 2048 + 1024 + c) * 8 + q1];
        }
    // phase-2 weights: Wp[g][qq][tid], f32
    float wpv[32];
#pragma unroll
    for (int j = 0; j < 32; ++j) wpv[j] = Wp[(size_t)j * H_DIM + tid];
    float bpv[4];
#pragma unroll
    for (int gg = 0; gg < 4; ++gg) bpv[gg] = bp[gg * H_DIM + tid];

    // stage gx[t][b][0..31] for all t (coalesced; 4 iters)
#pragma unroll
    for (int i = tid; i < T_LEN * 32; i += 1024)
        gxl[i] = gx[((size_t)(i >> 5) * B_SZ + b) * 32 + (i & 31)];

    hs[tid] = 0.f;                              // h_{-1} = 0
    float cx = 0.f;
    __syncthreads();

    for (int t = 0; t < T_LEN; ++t) {
        // ---- phase 1: raw[o0],raw[o1] = h . Wg_h[:,o] ----
        const float4* h4 = (const float4*)hs;
        float a0 = 0.f, a1 = 0.f;
#pragma unroll
        for (int j = 0; j < 4; ++j) {
            float4 v = h4[j * 64 + lane];
            a0 = fmaf(wA[4 * j + 0], v.x, a0); a1 = fmaf(wB[4 * j + 0], v.x, a1);
            a0 = fmaf(wA[4 * j + 1], v.y, a0); a1 = fmaf(wB[4 * j + 1], v.y, a1);
            a0 = fmaf(wA[4 * j + 2], v.z, a0); a1 = fmaf(wB[4 * j + 2], v.z, a1);
            a0 = fmaf(wA[4 * j + 3], v.w, a0); a1 = fmaf(wB[4 * j + 3], v.w, a1);
        }
#pragma unroll
        for (int d = 1; d < 64; d <<= 1) {
            a0 += __shfl_xor(a0, d, 64);
            a1 += __shfl_xor(a1, d, 64);
        }
        if (lane == 0) {
            qs[o0] = __cosf(a0 + gxl[t * 32 + o0]);   // <Z> = cos(raw + theta)
            qs[o1] = __cosf(a1 + gxl[t * 32 + o1]);
        }
        __syncthreads();                          // B1: qs ready; all hs reads done

        // ---- phase 2: projection + gates, one h per thread ----
        const float4* q4 = (const float4*)qs;
        float pj[4];
#pragma unroll
        for (int gg = 0; gg < 4; ++gg) {
            float4 u = q4[2 * gg], v = q4[2 * gg + 1];
            pj[gg] = bpv[gg]
                   + u.x * wpv[gg * 8 + 0] + u.y * wpv[gg * 8 + 1]
                   + u.z * wpv[gg * 8 + 2] + u.w * wpv[gg * 8 + 3]
                   + v.x * wpv[gg * 8 + 4] + v.y * wpv[gg * 8 + 5]
                   + v.z * wpv[gg * 8 + 6] + v.w * wpv[gg * 8 + 7];
        }
        const float f_ = sigmoid_f(pj[0]);
        const float i_ = sigmoid_f(pj[1]);
        const float g_ = tanh_f(pj[2]);
        const float o_ = sigmoid_f(pj[3]);
        cx = f_ * cx + i_ * g_;
        const float hv = o_ * tanh_f(cx);
        hs[tid] = hv;
        hb[((size_t)t * B_SZ + b) * H_DIM + tid] = __float2bfloat16(hv);
        __syncthreads();                          // B2: hv visible for next phase 1
    }
}

// ---------- K3: tag GEMM  C(32768x1024 f32) = Hb(bf16) x W_tag(bf16) ----------
// 128x128 block tile, 4 waves in 2x2, 64x64 per wave (4x4 MFMA frags)
__global__ __launch_bounds__(256) void k_tag_gemm(const __hip_bfloat16* __restrict__ Hb,
                                                  const __hip_bfloat16* __restrict__ WtT,
                                                  float* __restrict__ out)
{
    __shared__ short As[128 * 32];   // [row][k] bf16, unpadded (global_load_lds layout)
    __shared__ short Bs[128 * 32];   // [n][k]   bf16
    const int m0 = blockIdx.x * 128, n0 = blockIdx.y * 128;
    const int tid = threadIdx.x, lane = tid & 63, wid = tid >> 6;
    const int wm = (wid & 1) * 64, wn = (wid >> 1) * 64;
    const int mrow = lane & 15, quad = lane >> 4;

    const short* Hs = (const short*)Hb;
    const short* Ws = (const short*)WtT;

    f32x4 acc[4][4];
#pragma unroll
    for (int mi = 0; mi < 4; ++mi)
#pragma unroll
        for (int ni = 0; ni < 4; ++ni)
            acc[mi][ni] = (f32x4){0.f, 0.f, 0.f, 0.f};

    for (int kt = 0; kt < 32; ++kt) {
        const int k0 = kt * 32;
        __syncthreads();   // protect LDS from previous iteration's readers
#pragma unroll
        for (int ch = 0; ch < 2; ++ch) {
            const int chunk = wid + ch * 4;                 // 0..7
            const int row = chunk * 16 + (lane >> 2);
            const int kc = (lane & 3) * 8;
            gload_lds16(&As[chunk * 512], &Hs[(size_t)(m0 + row) * H_DIM + k0 + kc]);
            gload_lds16(&Bs[chunk * 512], &Ws[(size_t)(n0 + row) * H_DIM + k0 + kc]);
        }
        __syncthreads();   // compiler drains vmcnt before barrier

        short8 afr[4], bfr[4];
#pragma unroll
        for (int mi = 0; mi < 4; ++mi)
            afr[mi] = *(const short8*)&As[(wm + mi * 16 + mrow) * 32 + quad * 8];
#pragma unroll
        for (int ni = 0; ni < 4; ++ni)
            bfr[ni] = *(const short8*)&Bs[(wn + ni * 16 + mrow) * 32 + quad * 8];
#pragma unroll
        for (int mi = 0; mi < 4; ++mi)
#pragma unroll
            for (int ni = 0; ni < 4; ++ni)
                acc[mi][ni] = __builtin_amdgcn_mfma_f32_16x16x32_bf16(
                    afr[mi], bfr[ni], acc[mi][ni], 0, 0, 0);
    }

    // epilogue: D row = quad*4 + r, col = lane&15  (no bias: b_tag cancels in log_softmax)
#pragma unroll
    for (int mi = 0; mi < 4; ++mi)
#pragma unroll
        for (int ni = 0; ni < 4; ++ni)
#pragma unroll
            for (int r = 0; r < 4; ++r) {
                const int grow = m0 + wm + mi * 16 + quad * 4 + r;
                const int gcol = n0 + wn + ni * 16 + mrow;
                out[(size_t)grow * TAGS + gcol] = acc[mi][ni][r];
            }
}

// ---------- K4: log_softmax over batch axis (axis=1 of (T,B,TAGS)), in-place ----------
__global__ __launch_bounds__(256) void k_logsoftmax(float* __restrict__ out) {
    const int t = blockIdx.x;
    const int n = blockIdx.y * 256 + threadIdx.x;
    float* base = out + (size_t)t * B_SZ * TAGS + n;
    float m = -1e30f;
    for (int b = 0; b < B_SZ; ++b) m = fmaxf(m, base[(size_t)b * TAGS]);
    float s = 0.f;
    for (int b = 0; b < B_SZ; ++b) s += __expf(base[(size_t)b * TAGS] - m);
    const float lse = m + __logf(s);
    for (int b = 0; b < B_SZ; ++b) base[(size_t)b * TAGS] -= lse;
}

extern "C" void kernel_launch(void* const* d_in, const int* in_sizes, int n_in,
                              void* d_out, int out_size, void* d_ws, size_t ws_size,
                              hipStream_t stream) {
    (void)in_sizes; (void)n_in; (void)out_size; (void)ws_size;
    const int*   sent  = (const int*)d_in[0];
    const float* emb   = (const float*)d_in[1];
    const float* Wg    = (const float*)d_in[2];
    const float* bg    = (const float*)d_in[3];
    const float* theta = (const float*)d_in[4];
    const float* Wp    = (const float*)d_in[5];
    const float* bp    = (const float*)d_in[6];
    const float* Wt    = (const float*)d_in[7];
    // d_in[8] = b_tag: constant along the softmax (batch) axis -> cancels exactly.
    float* out = (float*)d_out;

    __hip_bfloat16* hb  = (__hip_bfloat16*)d_ws;                                     // 64 MB: lstm_out bf16
    __hip_bfloat16* WtT = (__hip_bfloat16*)((char*)d_ws + (size_t)64 * 1024 * 1024); // 2 MB: W_tag^T bf16
    // gx scratch (4 MB) lives in the FIRST part of the out buffer: it is consumed by
    // k_qlstm before k_tag_gemm overwrites out. No extra workspace needed.
    float* gx = (float*)d_out;

    k_wt_transpose<<<dim3(32, 32), 256, 0, stream>>>(Wt, WtT);
    k_gx<<<dim3(256), 1024, 0, stream>>>(sent, emb, Wg, bg, theta, gx);
    k_qlstm<<<dim3(B_SZ), 1024, 0, stream>>>(gx, Wg, Wp, bp, hb);
    k_tag_gemm<<<dim3(256, 8), 256, 0, stream>>>(hb, WtT, out);
    k_logsoftmax<<<dim3(T_LEN, 4), 256, 0, stream>>>(out);
}

// Round 2
// 691.250 us; speedup vs baseline: 1.1378x; 1.1378x over previous
//
#include <hip/hip_runtime.h>
#include <hip/hip_bf16.h>
#include <stdint.h>

// Problem dims (fixed by reference)
#define T_LEN 128
#define B_SZ  256
#define D_IN  1024
#define H_DIM 1024
#define NQ    8
#define VOCAB 32000
#define TAGS  1024

typedef __attribute__((ext_vector_type(8))) short short8;   // 8 bf16 (4 VGPRs)
typedef __attribute__((ext_vector_type(4))) float f32x4;

// ---------- helpers ----------
__device__ __forceinline__ unsigned short f2bf_bits(float x) {
    __hip_bfloat16 h = __float2bfloat16(x);
    unsigned short u; __builtin_memcpy(&u, &h, 2); return u;
}
__device__ __forceinline__ uint32_t pack_bf2(float a, float b) {
    return (uint32_t)f2bf_bits(a) | ((uint32_t)f2bf_bits(b) << 16);
}
__device__ __forceinline__ float sigmoid_f(float x) {
    return 1.f / (1.f + __expf(-x));
}
__device__ __forceinline__ float tanh_f(float x) {
    // 1 - 2/(e^{2x}+1); saturates correctly at +/-1 (inf-safe)
    return 1.f - 2.f / (__expf(2.f * x) + 1.f);
}
__device__ __forceinline__ void gload_lds16(void* lds_base, const void* gptr) {
    __builtin_amdgcn_global_load_lds(
        (__attribute__((address_space(1))) const void*)gptr,
        (__attribute__((address_space(3))) void*)lds_base,
        16, 0, 0);
}

// ---------- K0: W_tag (K x N fp32) -> WtT (N x K bf16) ----------
__global__ __launch_bounds__(256) void k_wt_transpose(const float* __restrict__ W,
                                                      __hip_bfloat16* __restrict__ WtT) {
    __shared__ float tile[32][33];
    const int kb = blockIdx.x * 32, nb = blockIdx.y * 32;
    const int r = threadIdx.x >> 5, c = threadIdx.x & 31;
#pragma unroll
    for (int i = 0; i < 4; ++i)
        tile[r + 8 * i][c] = W[(size_t)(kb + r + 8 * i) * TAGS + nb + c];
    __syncthreads();
#pragma unroll
    for (int i = 0; i < 4; ++i)
        WtT[(size_t)(nb + r + 8 * i) * H_DIM + kb + c] = __float2bfloat16(tile[c][r + 8 * i]);
}

// ---------- K1: gx[r][o] = emb[sent[r]] . Wg_x[:,o] + bg[o] + theta[o] ----------
// Parallel version: 1024 blocks x 256 thr (4 waves), 32 rows/block, 1 barrier/row.
// Wave wv owns outputs 8wv..8wv+7: lane = (slice s = l>>3, output ol = l&7).
// Per lane: 128 weight f32 in regs, 32 conflict-free b128 LDS reads (bank = 4s, 8-way
// ol-broadcast), 3-level shfl_xor reduce over s. x double-buffered in LDS; gx store
// delayed one row so its ack retires under the next row's dot.
#define GXB_ROWS 32
__global__ __launch_bounds__(256, 2) void k_gx(
    const int* __restrict__ sent, const float* __restrict__ emb,
    const float* __restrict__ Wg, const float* __restrict__ bg,
    const float* __restrict__ theta, float* __restrict__ gx)
{
    __shared__ float xs[2][1024];
    const int tid = threadIdx.x, lane = tid & 63, wv = tid >> 6;
    const int ol = lane & 7, s = lane >> 3;         // output-local, slice
    const int o = wv * 8 + ol;                      // g = wv, q = ol

    float wk[128];
#pragma unroll
    for (int k = 0; k < 32; ++k)
#pragma unroll
        for (int e = 0; e < 4; ++e) {
            const int c = (s + 8 * k) * 4 + e;      // x part: rows [0,1024)
            wk[4 * k + e] = Wg[((size_t)wv * 2048 + c) * 8 + ol];
        }
    const float bt = bg[o] + theta[o];

    const int rbase = blockIdx.x * GXB_ROWS;
    const float4* emb4 = (const float4*)emb;
    float4 xn = emb4[(size_t)sent[rbase] * 256 + tid];
    *(float4*)&xs[0][4 * tid] = xn;
    __syncthreads();

    float aPrev = 0.f; int rPrev = -1;
    int cur = 0;
    for (int i = 0; i < GXB_ROWS; ++i) {
        if (i + 1 < GXB_ROWS)
            xn = emb4[(size_t)sent[rbase + i + 1] * 256 + tid];   // prefetch
        if (rPrev >= 0 && lane < 8)
            gx[(size_t)rPrev * 32 + wv * 8 + lane] = aPrev;       // delayed store

        const float4* x4 = (const float4*)xs[cur];
        float a0 = 0.f, a1 = 0.f, a2 = 0.f, a3 = 0.f;
#pragma unroll
        for (int k = 0; k < 32; ++k) {
            float4 v = x4[s + 8 * k];
            a0 = fmaf(wk[4 * k + 0], v.x, a0);
            a1 = fmaf(wk[4 * k + 1], v.y, a1);
            a2 = fmaf(wk[4 * k + 2], v.z, a2);
            a3 = fmaf(wk[4 * k + 3], v.w, a3);
        }
        float a = (a0 + a1) + (a2 + a3);
#pragma unroll
        for (int d = 8; d < 64; d <<= 1) a += __shfl_xor(a, d, 64);
        aPrev = a + bt; rPrev = rbase + i;

        if (i + 1 < GXB_ROWS)
            *(float4*)&xs[cur ^ 1][4 * tid] = xn;   // other buffer: safe pre-barrier
        __syncthreads();
        cur ^= 1;
    }
    if (lane < 8) gx[(size_t)rPrev * 32 + wv * 8 + lane] = aPrev;
}

// ---------- K2: recurrent QLSTM (h-part only). one block (512 thr) per batch ----------
// 8 waves. Phase 1: wave wv owns outputs 4wv..4wv+3; lane = (slice s = l>>2, output
// ol = l&3); 64 f32 weights in regs, 16 b128 LDS reads (2-way conflict: free-ish),
// 4-level butterfly. Phase 2: 2 adjacent h per thread -> hb store is one packed dword,
// DELAYED one step (issued at loop top) so its vmcnt-ack retires under phase 1 instead
// of stalling the barrier. B1 drains vm+lgkm; B2 is lgkm-only.
__global__ __launch_bounds__(512, 2) void k_qlstm(
    const float* __restrict__ gx, const float* __restrict__ Wg,
    const float* __restrict__ Wp, const float* __restrict__ bp,
    __hip_bfloat16* __restrict__ hb)
{
    __shared__ float hs[1024];
    __shared__ __attribute__((aligned(16))) float qs[32];
    __shared__ float gxl[T_LEN * 32];          // 16 KB: this block's gx slice

    const int tid = threadIdx.x, lane = tid & 63, wv = tid >> 6;
    const int b = blockIdx.x;
    const int ol = lane & 3, s = lane >> 2;    // output-local, slice
    const int o = 4 * wv + ol;
    const int g = o >> 3, q = o & 7;

    // phase-1 weights: h part of Wg (rows 1024..2047), f32 in regs
    float wg[64];
#pragma unroll
    for (int k = 0; k < 16; ++k)
#pragma unroll
        for (int e = 0; e < 4; ++e) {
            const int c = (s + 16 * k) * 4 + e;
            wg[4 * k + e] = Wg[((size_t)g * 2048 + 1024 + c) * 8 + q];
        }
    // phase-2 weights: Wp[.][.][h] for h = 2*tid, 2*tid+1
    float wpA[32], wpB[32];
#pragma unroll
    for (int j = 0; j < 32; ++j) {
        wpA[j] = Wp[(size_t)j * H_DIM + 2 * tid];
        wpB[j] = Wp[(size_t)j * H_DIM + 2 * tid + 1];
    }
    float bpA[4], bpB[4];
#pragma unroll
    for (int gg = 0; gg < 4; ++gg) {
        bpA[gg] = bp[gg * H_DIM + 2 * tid];
        bpB[gg] = bp[gg * H_DIM + 2 * tid + 1];
    }

    // stage gx[t][b][0..31] for all t
#pragma unroll
    for (int i = tid; i < T_LEN * 32; i += 512)
        gxl[i] = gx[((size_t)(i >> 5) * B_SZ + b) * 32 + (i & 31)];

    *(float2*)&hs[2 * tid] = (float2){0.f, 0.f};   // h_{-1} = 0
    float cx0 = 0.f, cx1 = 0.f;
    uint32_t hvp = 0;                              // prev step's packed (hv0,hv1)
    __syncthreads();

    uint32_t* hb32 = (uint32_t*)hb;
    for (int t = 0; t < T_LEN; ++t) {
        // delayed hb store for step t-1: ack retires under this step's phase 1
        if (t > 0)
            hb32[((size_t)(t - 1) * B_SZ + b) * 512 + tid] = hvp;

        // ---- phase 1: raw[o] = h . Wg_h[:,o] ----
        const float4* h4 = (const float4*)hs;
        float a0 = 0.f, a1 = 0.f, a2 = 0.f, a3 = 0.f;
#pragma unroll
        for (int k = 0; k < 16; ++k) {
            float4 v = h4[s + 16 * k];
            a0 = fmaf(wg[4 * k + 0], v.x, a0);
            a1 = fmaf(wg[4 * k + 1], v.y, a1);
            a2 = fmaf(wg[4 * k + 2], v.z, a2);
            a3 = fmaf(wg[4 * k + 3], v.w, a3);
        }
        float a = (a0 + a1) + (a2 + a3);
#pragma unroll
        for (int d = 4; d < 64; d <<= 1) a += __shfl_xor(a, d, 64);
        if (lane < 4)                               // s==0 lanes hold ol=0..3
            qs[4 * wv + lane] = __cosf(a + gxl[t * 32 + 4 * wv + lane]);
        __syncthreads();                            // B1 (vm drain: store is old)

        // ---- phase 2: projection + gates, h = 2*tid, 2*tid+1 ----
        const float4* q4 = (const float4*)qs;
        float pjA[4], pjB[4];
#pragma unroll
        for (int gg = 0; gg < 4; ++gg) {
            float4 u = q4[2 * gg], v = q4[2 * gg + 1];
            pjA[gg] = bpA[gg]
                    + u.x * wpA[gg * 8 + 0] + u.y * wpA[gg * 8 + 1]
                    + u.z * wpA[gg * 8 + 2] + u.w * wpA[gg * 8 + 3]
                    + v.x * wpA[gg * 8 + 4] + v.y * wpA[gg * 8 + 5]
                    + v.z * wpA[gg * 8 + 6] + v.w * wpA[gg * 8 + 7];
            pjB[gg] = bpB[gg]
                    + u.x * wpB[gg * 8 + 0] + u.y * wpB[gg * 8 + 1]
                    + u.z * wpB[gg * 8 + 2] + u.w * wpB[gg * 8 + 3]
                    + v.x * wpB[gg * 8 + 4] + v.y * wpB[gg * 8 + 5]
                    + v.z * wpB[gg * 8 + 6] + v.w * wpB[gg * 8 + 7];
        }
        const float fA = sigmoid_f(pjA[0]), iA = sigmoid_f(pjA[1]);
        const float gA = tanh_f(pjA[2]),   oA = sigmoid_f(pjA[3]);
        const float fB = sigmoid_f(pjB[0]), iB = sigmoid_f(pjB[1]);
        const float gB = tanh_f(pjB[2]),   oB = sigmoid_f(pjB[3]);
        cx0 = fA * cx0 + iA * gA;
        cx1 = fB * cx1 + iB * gB;
        const float hv0 = oA * tanh_f(cx0);
        const float hv1 = oB * tanh_f(cx1);
        *(float2*)&hs[2 * tid] = (float2){hv0, hv1};
        hvp = pack_bf2(hv0, hv1);
        __syncthreads();                            // B2 (lgkm only: no vm issued)
    }
    hb32[((size_t)(T_LEN - 1) * B_SZ + b) * 512 + tid] = hvp;
}

// ---------- K3: tag GEMM  C(32768x1024 f32) = Hb(bf16) x W_tag(bf16) ----------
// 128x128 block tile, 4 waves in 2x2, 64x64 per wave (4x4 MFMA frags)
__global__ __launch_bounds__(256) void k_tag_gemm(const __hip_bfloat16* __restrict__ Hb,
                                                  const __hip_bfloat16* __restrict__ WtT,
                                                  float* __restrict__ out)
{
    __shared__ short As[128 * 32];   // [row][k] bf16, unpadded (global_load_lds layout)
    __shared__ short Bs[128 * 32];   // [n][k]   bf16
    const int m0 = blockIdx.x * 128, n0 = blockIdx.y * 128;
    const int tid = threadIdx.x, lane = tid & 63, wid = tid >> 6;
    const int wm = (wid & 1) * 64, wn = (wid >> 1) * 64;
    const int mrow = lane & 15, quad = lane >> 4;

    const short* Hs = (const short*)Hb;
    const short* Ws = (const short*)WtT;

    f32x4 acc[4][4];
#pragma unroll
    for (int mi = 0; mi < 4; ++mi)
#pragma unroll
        for (int ni = 0; ni < 4; ++ni)
            acc[mi][ni] = (f32x4){0.f, 0.f, 0.f, 0.f};

    for (int kt = 0; kt < 32; ++kt) {
        const int k0 = kt * 32;
        __syncthreads();   // protect LDS from previous iteration's readers
#pragma unroll
        for (int ch = 0; ch < 2; ++ch) {
            const int chunk = wid + ch * 4;                 // 0..7
            const int row = chunk * 16 + (lane >> 2);
            const int kc = (lane & 3) * 8;
            gload_lds16(&As[chunk * 512], &Hs[(size_t)(m0 + row) * H_DIM + k0 + kc]);
            gload_lds16(&Bs[chunk * 512], &Ws[(size_t)(n0 + row) * H_DIM + k0 + kc]);
        }
        __syncthreads();   // compiler drains vmcnt before barrier

        short8 afr[4], bfr[4];
#pragma unroll
        for (int mi = 0; mi < 4; ++mi)
            afr[mi] = *(const short8*)&As[(wm + mi * 16 + mrow) * 32 + quad * 8];
#pragma unroll
        for (int ni = 0; ni < 4; ++ni)
            bfr[ni] = *(const short8*)&Bs[(wn + ni * 16 + mrow) * 32 + quad * 8];
#pragma unroll
        for (int mi = 0; mi < 4; ++mi)
#pragma unroll
            for (int ni = 0; ni < 4; ++ni)
                acc[mi][ni] = __builtin_amdgcn_mfma_f32_16x16x32_bf16(
                    afr[mi], bfr[ni], acc[mi][ni], 0, 0, 0);
    }

    // epilogue: D row = quad*4 + r, col = lane&15  (no bias: b_tag cancels in log_softmax)
#pragma unroll
    for (int mi = 0; mi < 4; ++mi)
#pragma unroll
        for (int ni = 0; ni < 4; ++ni)
#pragma unroll
            for (int r = 0; r < 4; ++r) {
                const int grow = m0 + wm + mi * 16 + quad * 4 + r;
                const int gcol = n0 + wn + ni * 16 + mrow;
                out[(size_t)grow * TAGS + gcol] = acc[mi][ni][r];
            }
}

// ---------- K4: log_softmax over batch axis (axis=1 of (T,B,TAGS)), in-place ----------
__global__ __launch_bounds__(256) void k_logsoftmax(float* __restrict__ out) {
    const int t = blockIdx.x;
    const int n = blockIdx.y * 256 + threadIdx.x;
    float* base = out + (size_t)t * B_SZ * TAGS + n;
    float m = -1e30f;
    for (int b = 0; b < B_SZ; ++b) m = fmaxf(m, base[(size_t)b * TAGS]);
    float s = 0.f;
    for (int b = 0; b < B_SZ; ++b) s += __expf(base[(size_t)b * TAGS] - m);
    const float lse = m + __logf(s);
    for (int b = 0; b < B_SZ; ++b) base[(size_t)b * TAGS] -= lse;
}

extern "C" void kernel_launch(void* const* d_in, const int* in_sizes, int n_in,
                              void* d_out, int out_size, void* d_ws, size_t ws_size,
                              hipStream_t stream) {
    (void)in_sizes; (void)n_in; (void)out_size; (void)ws_size;
    const int*   sent  = (const int*)d_in[0];
    const float* emb   = (const float*)d_in[1];
    const float* Wg    = (const float*)d_in[2];
    const float* bg    = (const float*)d_in[3];
    const float* theta = (const float*)d_in[4];
    const float* Wp    = (const float*)d_in[5];
    const float* bp    = (const float*)d_in[6];
    const float* Wt    = (const float*)d_in[7];
    // d_in[8] = b_tag: constant along the softmax (batch) axis -> cancels exactly.
    float* out = (float*)d_out;

    __hip_bfloat16* hb  = (__hip_bfloat16*)d_ws;                                     // 64 MB: lstm_out bf16
    __hip_bfloat16* WtT = (__hip_bfloat16*)((char*)d_ws + (size_t)64 * 1024 * 1024); // 2 MB: W_tag^T bf16
    // gx scratch (4 MB) lives in the FIRST part of the out buffer: it is consumed by
    // k_qlstm before k_tag_gemm overwrites out. No extra workspace needed.
    float* gx = (float*)d_out;

    k_wt_transpose<<<dim3(32, 32), 256, 0, stream>>>(Wt, WtT);
    k_gx<<<dim3((T_LEN * B_SZ) / GXB_ROWS), 256, 0, stream>>>(sent, emb, Wg, bg, theta, gx);
    k_qlstm<<<dim3(B_SZ), 512, 0, stream>>>(gx, Wg, Wp, bp, hb);
    k_tag_gemm<<<dim3(256, 8), 256, 0, stream>>>(hb, WtT, out);
    k_logsoftmax<<<dim3(T_LEN, 4), 256, 0, stream>>>(out);
}

// Round 4
// 628.337 us; speedup vs baseline: 1.2517x; 1.1001x over previous
//
#include <hip/hip_runtime.h>
#include <hip/hip_bf16.h>
#include <stdint.h>

// Problem dims (fixed by reference)
#define T_LEN 128
#define B_SZ  256
#define D_IN  1024
#define H_DIM 1024
#define NQ    8
#define VOCAB 32000
#define TAGS  1024

typedef __attribute__((ext_vector_type(8))) short short8;   // 8 bf16 (4 VGPRs)
typedef __attribute__((ext_vector_type(4))) float f32x4;

// ---------- helpers ----------
__device__ __forceinline__ unsigned short f2bf_bits(float x) {
    __hip_bfloat16 h = __float2bfloat16(x);
    unsigned short u; __builtin_memcpy(&u, &h, 2); return u;
}
__device__ __forceinline__ uint32_t pack_bf2(float a, float b) {
    return (uint32_t)f2bf_bits(a) | ((uint32_t)f2bf_bits(b) << 16);
}
__device__ __forceinline__ float sigmoid_f(float x) {
    return 1.f / (1.f + __expf(-x));
}
__device__ __forceinline__ float tanh_f(float x) {
    // 1 - 2/(e^{2x}+1); saturates correctly at +/-1 (inf-safe)
    return 1.f - 2.f / (__expf(2.f * x) + 1.f);
}
__device__ __forceinline__ void gload_lds16(void* lds_base, const void* gptr) {
    __builtin_amdgcn_global_load_lds(
        (__attribute__((address_space(1))) const void*)gptr,
        (__attribute__((address_space(3))) void*)lds_base,
        16, 0, 0);
}

// ---------- K0: W_tag (K x N fp32) -> WtT (N x K bf16) ----------
__global__ __launch_bounds__(256) void k_wt_transpose(const float* __restrict__ W,
                                                      __hip_bfloat16* __restrict__ WtT) {
    __shared__ float tile[32][33];
    const int kb = blockIdx.x * 32, nb = blockIdx.y * 32;
    const int r = threadIdx.x >> 5, c = threadIdx.x & 31;
#pragma unroll
    for (int i = 0; i < 4; ++i)
        tile[r + 8 * i][c] = W[(size_t)(kb + r + 8 * i) * TAGS + nb + c];
    __syncthreads();
#pragma unroll
    for (int i = 0; i < 4; ++i)
        WtT[(size_t)(nb + r + 8 * i) * H_DIM + kb + c] = __float2bfloat16(tile[c][r + 8 * i]);
}

// ---------- K1: gx[r][o] = emb[sent[r]] . Wg_x[:,o] + bg[o] + theta[o] ----------
// 256 blocks x 256 thr (4 waves), 32 rows/block, 1 barrier/row. Wave wv owns outputs
// 8wv..8wv+7 (lane = slice s = l>>3, output ol = l&7); 128 f32 weights in regs;
// 3-level shfl_xor reduce. gx stores batched x8 in regs so the vmcnt(0) drain at
// __syncthreads happens once per 8 rows, not every row.
#define GXB_ROWS 32
__global__ __launch_bounds__(256, 2) void k_gx(
    const int* __restrict__ sent, const float* __restrict__ emb,
    const float* __restrict__ Wg, const float* __restrict__ bg,
    const float* __restrict__ theta, float* __restrict__ gx)
{
    __shared__ float xs[2][1024];
    const int tid = threadIdx.x, lane = tid & 63, wv = tid >> 6;
    const int ol = lane & 7, s = lane >> 3;         // output-local, slice
    const int o = wv * 8 + ol;                      // g = wv, q = ol

    float wk[128];
#pragma unroll
    for (int k = 0; k < 32; ++k)
#pragma unroll
        for (int e = 0; e < 4; ++e) {
            const int c = (s + 8 * k) * 4 + e;      // x part: rows [0,1024)
            wk[4 * k + e] = Wg[((size_t)wv * 2048 + c) * 8 + ol];
        }
    const float bt = bg[o] + theta[o];

    const int rbase = blockIdx.x * GXB_ROWS;
    const float4* emb4 = (const float4*)emb;
    float4 xn = emb4[(size_t)sent[rbase] * 256 + tid];
    *(float4*)&xs[0][4 * tid] = xn;
    __syncthreads();

    int cur = 0;
    for (int i8 = 0; i8 < GXB_ROWS / 8; ++i8) {
        float gacc[8];
#pragma unroll
        for (int ii = 0; ii < 8; ++ii) {
            const int i = i8 * 8 + ii;
            const bool havenext = (i + 1 < GXB_ROWS);
            if (havenext)
                xn = emb4[(size_t)sent[rbase + i + 1] * 256 + tid];   // prefetch

            const float4* x4 = (const float4*)xs[cur];
            float a0 = 0.f, a1 = 0.f, a2 = 0.f, a3 = 0.f;
#pragma unroll
            for (int k = 0; k < 32; ++k) {
                float4 v = x4[s + 8 * k];
                a0 = fmaf(wk[4 * k + 0], v.x, a0);
                a1 = fmaf(wk[4 * k + 1], v.y, a1);
                a2 = fmaf(wk[4 * k + 2], v.z, a2);
                a3 = fmaf(wk[4 * k + 3], v.w, a3);
            }
            float a = (a0 + a1) + (a2 + a3);
#pragma unroll
            for (int d = 8; d < 64; d <<= 1) a += __shfl_xor(a, d, 64);
            gacc[ii] = a + bt;

            if (havenext)
                *(float4*)&xs[cur ^ 1][4 * tid] = xn;   // other buffer: pre-barrier OK
            __syncthreads();
            cur ^= 1;
        }
        if (lane < 8) {
#pragma unroll
            for (int ii = 0; ii < 8; ++ii)
                gx[(size_t)(rbase + i8 * 8 + ii) * 32 + wv * 8 + lane] = gacc[ii];
        }
    }
}

// ---------- K2: recurrent QLSTM (h-part only). one block (512 thr) per batch ----------
// Phase 1 on MFMA: h kept packed-bf16 in LDS; wave wv owns k-slice [128wv,128wv+128):
// 4 broadcast ds_read_b128 (B-frag = h, all 16 cols identical) + 8 mfma_16x16x32_bf16
// with A = Wg_h^T frags preloaded in regs. Partials -> red[8][32]; 32-thread stage
// sums + cos -> qs. Phase 2: per-thread f32 projection + gates (2 h/thread). hb
// stores batched x8 in static-indexed regs so the pre-barrier vmcnt(0) drain costs
// once per 8 steps. 3 short barriers/step; no butterfly, no full-spread LDS reads.
__global__ __launch_bounds__(512, 2) void k_qlstm(
    const float* __restrict__ gx, const float* __restrict__ Wg,
    const float* __restrict__ Wp, const float* __restrict__ bp,
    __hip_bfloat16* __restrict__ hb)
{
    __shared__ uint32_t hsb[512];              // h as packed bf16 pairs (2 KB)
    __shared__ float red[8 * 32];              // per-wave raw partials
    __shared__ __attribute__((aligned(16))) float qs[32];
    __shared__ float gxl[T_LEN * 32];          // 16 KB: this block's gx slice

    const int tid = threadIdx.x, lane = tid & 63, wv = tid >> 6;
    const int b = blockIdx.x;
    const int lg = lane >> 4;                  // k-octet group 0..3
    const int K0 = wv * 128;                   // this wave's h-slice base

    // --- phase-1 weights as MFMA A-frags: A[r][k'] = Wg_h[k0+k'][obase+r] ---
    // lane l holds A[l&15][lg*8+j], j=0..7 (bf16 pairs), per (ro, kt)
    union { short8 s8; uint32_t u[4]; } wf[2][4];
#pragma unroll
    for (int ro = 0; ro < 2; ++ro) {
        const int o = ro * 16 + (lane & 15);
        const int g = o >> 3, q = o & 7;
#pragma unroll
        for (int kt = 0; kt < 4; ++kt) {
            const int k0 = K0 + kt * 32 + lg * 8;
#pragma unroll
            for (int p = 0; p < 4; ++p) {
                float e0 = Wg[((size_t)g * 2048 + 1024 + k0 + 2 * p) * 8 + q];
                float e1 = Wg[((size_t)g * 2048 + 1024 + k0 + 2 * p + 1) * 8 + q];
                wf[ro][kt].u[p] = pack_bf2(e0, e1);
            }
        }
    }
    // --- phase-2 weights: Wp[.][.][h] for h = 2*tid, 2*tid+1 (f32) ---
    float wpA[32], wpB[32];
#pragma unroll
    for (int j = 0; j < 32; ++j) {
        wpA[j] = Wp[(size_t)j * H_DIM + 2 * tid];
        wpB[j] = Wp[(size_t)j * H_DIM + 2 * tid + 1];
    }
    float bpA[4], bpB[4];
#pragma unroll
    for (int gg = 0; gg < 4; ++gg) {
        bpA[gg] = bp[gg * H_DIM + 2 * tid];
        bpB[gg] = bp[gg * H_DIM + 2 * tid + 1];
    }

    // stage gx[t][b][0..31] for all t
    for (int i = tid; i < T_LEN * 32; i += 512)
        gxl[i] = gx[((size_t)(i >> 5) * B_SZ + b) * 32 + (i & 31)];

    hsb[tid] = 0u;                             // h_{-1} = 0 (bf16 0x0000 pair)
    float cx0 = 0.f, cx1 = 0.f;
    __syncthreads();

    uint32_t* hb32 = (uint32_t*)hb;
    const f32x4 zf = (f32x4){0.f, 0.f, 0.f, 0.f};

    for (int t8 = 0; t8 < T_LEN / 8; ++t8) {
        uint32_t hv8[8];
#pragma unroll
        for (int tt = 0; tt < 8; ++tt) {
            const int t = t8 * 8 + tt;

            // ---- phase 1: partial raw via MFMA (all waves, own k-slice) ----
            f32x4 p0 = zf, p1 = zf;
#pragma unroll
            for (int kt = 0; kt < 4; ++kt) {
                // B-frag: lane l reads h bf16 [K0+kt*32+lg*8 .. +8) -> 4 unique 16B
                short8 bf = *(const short8*)((const char*)hsb + 2 * K0 + 64 * kt + lg * 16);
                p0 = __builtin_amdgcn_mfma_f32_16x16x32_bf16(wf[0][kt].s8, bf, p0, 0, 0, 0);
                p1 = __builtin_amdgcn_mfma_f32_16x16x32_bf16(wf[1][kt].s8, bf, p1, 0, 0, 0);
            }
            // D: every col identical; lane with (l&15)==0 writes rows lg*4..lg*4+3
            if ((lane & 15) == 0) {
                *(f32x4*)&red[wv * 32 + 4 * lg] = p0;
                *(f32x4*)&red[wv * 32 + 16 + 4 * lg] = p1;
            }
            __syncthreads();                    // B1a: red ready

            // ---- stage: cross-wave sum + quantum cos (32 threads) ----
            if (tid < 32) {
                float r = gxl[t * 32 + tid];
#pragma unroll
                for (int w = 0; w < 8; ++w) r += red[w * 32 + tid];
                qs[tid] = __cosf(r);            // <Z> = cos(raw + theta)
            }
            __syncthreads();                    // B1b: qs ready

            // ---- phase 2: projection + gates, h = 2*tid, 2*tid+1 ----
            const float4* q4 = (const float4*)qs;
            float pjA[4], pjB[4];
#pragma unroll
            for (int gg = 0; gg < 4; ++gg) {
                float4 u = q4[2 * gg], v = q4[2 * gg + 1];
                pjA[gg] = bpA[gg]
                        + u.x * wpA[gg * 8 + 0] + u.y * wpA[gg * 8 + 1]
                        + u.z * wpA[gg * 8 + 2] + u.w * wpA[gg * 8 + 3]
                        + v.x * wpA[gg * 8 + 4] + v.y * wpA[gg * 8 + 5]
                        + v.z * wpA[gg * 8 + 6] + v.w * wpA[gg * 8 + 7];
                pjB[gg] = bpB[gg]
                        + u.x * wpB[gg * 8 + 0] + u.y * wpB[gg * 8 + 1]
                        + u.z * wpB[gg * 8 + 2] + u.w * wpB[gg * 8 + 3]
                        + v.x * wpB[gg * 8 + 4] + v.y * wpB[gg * 8 + 5]
                        + v.z * wpB[gg * 8 + 6] + v.w * wpB[gg * 8 + 7];
            }
            const float fA = sigmoid_f(pjA[0]), iA = sigmoid_f(pjA[1]);
            const float gA = tanh_f(pjA[2]),   oA = sigmoid_f(pjA[3]);
            const float fB = sigmoid_f(pjB[0]), iB = sigmoid_f(pjB[1]);
            const float gB = tanh_f(pjB[2]),   oB = sigmoid_f(pjB[3]);
            cx0 = fA * cx0 + iA * gA;
            cx1 = fB * cx1 + iB * gB;
            const float hv0 = oA * tanh_f(cx0);
            const float hv1 = oB * tanh_f(cx1);
            const uint32_t hvp = pack_bf2(hv0, hv1);
            hsb[tid] = hvp;                     // bf16 h for next step's MFMA
            hv8[tt] = hvp;                      // static index (rule #20)
            __syncthreads();                    // B2: h ready
        }
        // flush 8 steps of hb: the vmcnt(0) drain at the next barrier costs once/8
#pragma unroll
        for (int tt = 0; tt < 8; ++tt)
            hb32[((size_t)(t8 * 8 + tt) * B_SZ + b) * 512 + tid] = hv8[tt];
    }
}

// ---------- K3: tag GEMM  C(32768x1024 f32) = Hb(bf16) x W_tag(bf16) ----------
// 128x128 block tile, 4 waves in 2x2, 64x64 per wave (4x4 MFMA frags)
__global__ __launch_bounds__(256) void k_tag_gemm(const __hip_bfloat16* __restrict__ Hb,
                                                  const __hip_bfloat16* __restrict__ WtT,
                                                  float* __restrict__ out)
{
    __shared__ short As[128 * 32];   // [row][k] bf16, unpadded (global_load_lds layout)
    __shared__ short Bs[128 * 32];   // [n][k]   bf16
    const int m0 = blockIdx.x * 128, n0 = blockIdx.y * 128;
    const int tid = threadIdx.x, lane = tid & 63, wid = tid >> 6;
    const int wm = (wid & 1) * 64, wn = (wid >> 1) * 64;
    const int mrow = lane & 15, quad = lane >> 4;

    const short* Hs = (const short*)Hb;
    const short* Ws = (const short*)WtT;

    f32x4 acc[4][4];
#pragma unroll
    for (int mi = 0; mi < 4; ++mi)
#pragma unroll
        for (int ni = 0; ni < 4; ++ni)
            acc[mi][ni] = (f32x4){0.f, 0.f, 0.f, 0.f};

    for (int kt = 0; kt < 32; ++kt) {
        const int k0 = kt * 32;
        __syncthreads();   // protect LDS from previous iteration's readers
#pragma unroll
        for (int ch = 0; ch < 2; ++ch) {
            const int chunk = wid + ch * 4;                 // 0..7
            const int row = chunk * 16 + (lane >> 2);
            const int kc = (lane & 3) * 8;
            gload_lds16(&As[chunk * 512], &Hs[(size_t)(m0 + row) * H_DIM + k0 + kc]);
            gload_lds16(&Bs[chunk * 512], &Ws[(size_t)(n0 + row) * H_DIM + k0 + kc]);
        }
        __syncthreads();   // compiler drains vmcnt before barrier

        short8 afr[4], bfr[4];
#pragma unroll
        for (int mi = 0; mi < 4; ++mi)
            afr[mi] = *(const short8*)&As[(wm + mi * 16 + mrow) * 32 + quad * 8];
#pragma unroll
        for (int ni = 0; ni < 4; ++ni)
            bfr[ni] = *(const short8*)&Bs[(wn + ni * 16 + mrow) * 32 + quad * 8];
#pragma unroll
        for (int mi = 0; mi < 4; ++mi)
#pragma unroll
            for (int ni = 0; ni < 4; ++ni)
                acc[mi][ni] = __builtin_amdgcn_mfma_f32_16x16x32_bf16(
                    afr[mi], bfr[ni], acc[mi][ni], 0, 0, 0);
    }

    // epilogue: D row = quad*4 + r, col = lane&15  (no bias: b_tag cancels in log_softmax)
#pragma unroll
    for (int mi = 0; mi < 4; ++mi)
#pragma unroll
        for (int ni = 0; ni < 4; ++ni)
#pragma unroll
            for (int r = 0; r < 4; ++r) {
                const int grow = m0 + wm + mi * 16 + quad * 4 + r;
                const int gcol = n0 + wn + ni * 16 + mrow;
                out[(size_t)grow * TAGS + gcol] = acc[mi][ni][r];
            }
}

// ---------- K4: log_softmax over batch axis (axis=1 of (T,B,TAGS)), in-place ----------
// LDS-staged: read the 256x32 column-tile once (32 KB), reduce in LDS, write once.
// Traffic 256 MB total vs 512 MB+ for the multi-pass version. 32 KB LDS stays well
// under the 64 KiB/WG boundary (the 64-col variant sat at 65.8 KB -> load-limit risk).
#define LSM_COLS 32
__global__ __launch_bounds__(256) void k_logsoftmax(float* __restrict__ out) {
    __shared__ float tile[256 * LSM_COLS];     // 32 KB
    __shared__ float lse[LSM_COLS];
    const int t = blockIdx.x, n0 = blockIdx.y * LSM_COLS;
    const int tid = threadIdx.x;
    float* base = out + (size_t)t * B_SZ * TAGS + n0;

    for (int i = tid; i < 256 * LSM_COLS; i += 256) {
        const int b = i >> 5, c = i & (LSM_COLS - 1);
        tile[i] = base[(size_t)b * TAGS + c];
    }
    __syncthreads();
    if (tid < LSM_COLS) {
        float m = -1e30f;
        for (int b = 0; b < 256; ++b) m = fmaxf(m, tile[b * LSM_COLS + tid]);
        float s = 0.f;
        for (int b = 0; b < 256; ++b) s += __expf(tile[b * LSM_COLS + tid] - m);
        lse[tid] = m + __logf(s);
    }
    __syncthreads();
    for (int i = tid; i < 256 * LSM_COLS; i += 256) {
        const int b = i >> 5, c = i & (LSM_COLS - 1);
        base[(size_t)b * TAGS + c] = tile[i] - lse[c];
    }
}

extern "C" void kernel_launch(void* const* d_in, const int* in_sizes, int n_in,
                              void* d_out, int out_size, void* d_ws, size_t ws_size,
                              hipStream_t stream) {
    (void)in_sizes; (void)n_in; (void)out_size; (void)ws_size;
    const int*   sent  = (const int*)d_in[0];
    const float* emb   = (const float*)d_in[1];
    const float* Wg    = (const float*)d_in[2];
    const float* bg    = (const float*)d_in[3];
    const float* theta = (const float*)d_in[4];
    const float* Wp    = (const float*)d_in[5];
    const float* bp    = (const float*)d_in[6];
    const float* Wt    = (const float*)d_in[7];
    // d_in[8] = b_tag: constant along the softmax (batch) axis -> cancels exactly.
    float* out = (float*)d_out;

    __hip_bfloat16* hb  = (__hip_bfloat16*)d_ws;                                     // 64 MB: lstm_out bf16
    __hip_bfloat16* WtT = (__hip_bfloat16*)((char*)d_ws + (size_t)64 * 1024 * 1024); // 2 MB: W_tag^T bf16
    // gx scratch (4 MB) lives in the FIRST part of the out buffer: it is consumed by
    // k_qlstm before k_tag_gemm overwrites out. No extra workspace needed.
    float* gx = (float*)d_out;

    k_wt_transpose<<<dim3(32, 32), 256, 0, stream>>>(Wt, WtT);
    k_gx<<<dim3((T_LEN * B_SZ) / GXB_ROWS), 256, 0, stream>>>(sent, emb, Wg, bg, theta, gx);
    k_qlstm<<<dim3(B_SZ), 512, 0, stream>>>(gx, Wg, Wp, bp, hb);
    k_tag_gemm<<<dim3(256, 8), 256, 0, stream>>>(hb, WtT, out);
    k_logsoftmax<<<dim3(T_LEN, TAGS / LSM_COLS), 256, 0, stream>>>(out);
}

// Round 5
// 574.290 us; speedup vs baseline: 1.3695x; 1.0941x over previous
//
#include <hip/hip_runtime.h>
#include <hip/hip_bf16.h>
#include <stdint.h>

// Problem dims (fixed by reference)
#define T_LEN 128
#define B_SZ  256
#define D_IN  1024
#define H_DIM 1024
#define NQ    8
#define VOCAB 32000
#define TAGS  1024

typedef __attribute__((ext_vector_type(8))) short short8;   // 8 bf16 (4 VGPRs)
typedef __attribute__((ext_vector_type(4))) float f32x4;

// ---------- helpers ----------
__device__ __forceinline__ unsigned short f2bf_bits(float x) {
    __hip_bfloat16 h = __float2bfloat16(x);
    unsigned short u; __builtin_memcpy(&u, &h, 2); return u;
}
__device__ __forceinline__ uint32_t pack_bf2(float a, float b) {
    return (uint32_t)f2bf_bits(a) | ((uint32_t)f2bf_bits(b) << 16);
}
__device__ __forceinline__ float sigmoid_f(float x) {
    return 1.f / (1.f + __expf(-x));
}
__device__ __forceinline__ float tanh_f(float x) {
    // 1 - 2/(e^{2x}+1); saturates correctly at +/-1 (inf-safe)
    return 1.f - 2.f / (__expf(2.f * x) + 1.f);
}
__device__ __forceinline__ void gload_lds16(void* lds_base, const void* gptr) {
    __builtin_amdgcn_global_load_lds(
        (__attribute__((address_space(1))) const void*)gptr,
        (__attribute__((address_space(3))) void*)lds_base,
        16, 0, 0);
}

// ---------- K0: W_tag (K x N fp32) -> WtT (N x K bf16) ----------
__global__ __launch_bounds__(256) void k_wt_transpose(const float* __restrict__ W,
                                                      __hip_bfloat16* __restrict__ WtT) {
    __shared__ float tile[32][33];
    const int kb = blockIdx.x * 32, nb = blockIdx.y * 32;
    const int r = threadIdx.x >> 5, c = threadIdx.x & 31;
#pragma unroll
    for (int i = 0; i < 4; ++i)
        tile[r + 8 * i][c] = W[(size_t)(kb + r + 8 * i) * TAGS + nb + c];
    __syncthreads();
#pragma unroll
    for (int i = 0; i < 4; ++i)
        WtT[(size_t)(nb + r + 8 * i) * H_DIM + kb + c] = __float2bfloat16(tile[c][r + 8 * i]);
}

// ---------- K1: gx[r][o] = emb[sent[r]] . Wg_x[:,o] + bg[o] + theta[o] ----------
#define GXB_ROWS 32
__global__ __launch_bounds__(256, 2) void k_gx(
    const int* __restrict__ sent, const float* __restrict__ emb,
    const float* __restrict__ Wg, const float* __restrict__ bg,
    const float* __restrict__ theta, float* __restrict__ gx)
{
    __shared__ float xs[2][1024];
    const int tid = threadIdx.x, lane = tid & 63, wv = tid >> 6;
    const int ol = lane & 7, s = lane >> 3;         // output-local, slice
    const int o = wv * 8 + ol;                      // g = wv, q = ol

    float wk[128];
#pragma unroll
    for (int k = 0; k < 32; ++k)
#pragma unroll
        for (int e = 0; e < 4; ++e) {
            const int c = (s + 8 * k) * 4 + e;      // x part: rows [0,1024)
            wk[4 * k + e] = Wg[((size_t)wv * 2048 + c) * 8 + ol];
        }
    const float bt = bg[o] + theta[o];

    const int rbase = blockIdx.x * GXB_ROWS;
    const float4* emb4 = (const float4*)emb;
    float4 xn = emb4[(size_t)sent[rbase] * 256 + tid];
    *(float4*)&xs[0][4 * tid] = xn;
    __syncthreads();

    int cur = 0;
    for (int i8 = 0; i8 < GXB_ROWS / 8; ++i8) {
        float gacc[8];
#pragma unroll
        for (int ii = 0; ii < 8; ++ii) {
            const int i = i8 * 8 + ii;
            const bool havenext = (i + 1 < GXB_ROWS);
            if (havenext)
                xn = emb4[(size_t)sent[rbase + i + 1] * 256 + tid];   // prefetch

            const float4* x4 = (const float4*)xs[cur];
            float a0 = 0.f, a1 = 0.f, a2 = 0.f, a3 = 0.f;
#pragma unroll
            for (int k = 0; k < 32; ++k) {
                float4 v = x4[s + 8 * k];
                a0 = fmaf(wk[4 * k + 0], v.x, a0);
                a1 = fmaf(wk[4 * k + 1], v.y, a1);
                a2 = fmaf(wk[4 * k + 2], v.z, a2);
                a3 = fmaf(wk[4 * k + 3], v.w, a3);
            }
            float a = (a0 + a1) + (a2 + a3);
#pragma unroll
            for (int d = 8; d < 64; d <<= 1) a += __shfl_xor(a, d, 64);
            gacc[ii] = a + bt;

            if (havenext)
                *(float4*)&xs[cur ^ 1][4 * tid] = xn;   // other buffer: pre-barrier OK
            __syncthreads();
            cur ^= 1;
        }
        if (lane < 8) {
#pragma unroll
            for (int ii = 0; ii < 8; ++ii)
                gx[(size_t)(rbase + i8 * 8 + ii) * 32 + wv * 8 + lane] = gacc[ii];
        }
    }
}

// ---------- K2: recurrent QLSTM v5. one block (256 thr / 4 waves) per batch ----------
// 2 barriers/step, NO serial section:
//  ph1: wave wv owns k-slice [256wv, 256wv+256): 8 broadcast ds_read_b128 of bf16 h +
//       16 mfma_16x16x32_bf16 (A = Wg_h^T frags in 64 VGPRs, 4 indep accum chains).
//       Partials -> red[4][36] (only lanes l&15==0 write). B1.
//  stage (REPLICATED per wave, no extra barrier): every wave reads the 4 partials for
//       output (lane&31), adds gx, cos, then broadcasts all 32 q's in-register via
//       32 __shfl -> qa[32].
//  ph2: 4 h per thread, f32 weights (128 VGPR, fine at 1 wave/SIMD); gates; h ->
//       packed bf16 pairs in LDS (uint2 write). B2.
//  hb stores batched x8 in static regs -> vmcnt drain once per 8 steps.
__global__ __launch_bounds__(256, 1) void k_qlstm(
    const float* __restrict__ gx, const float* __restrict__ Wg,
    const float* __restrict__ Wp, const float* __restrict__ bp,
    __hip_bfloat16* __restrict__ hb)
{
    __shared__ uint32_t hsb[512];              // h as packed bf16 pairs (2 KB)
    __shared__ float red[4 * 36];              // per-wave partials, stride 36 (16B-aligned rows)
    __shared__ float gxl[T_LEN * 32];          // 16 KB: this block's gx slice

    const int tid = threadIdx.x, lane = tid & 63, wv = tid >> 6;
    const int b = blockIdx.x;
    const int lg = lane >> 4;                  // k-octet group 0..3
    const int K0 = wv * 256;                   // this wave's h-slice base
    const int ol = lane & 31;                  // output index for stage

    // --- phase-1 weights as MFMA A-frags: lane l holds A[l&15][lg*8+j] ---
    union { short8 s8; uint32_t u[4]; } wf[2][8];
#pragma unroll
    for (int ro = 0; ro < 2; ++ro) {
        const int o = ro * 16 + (lane & 15);
        const int g = o >> 3, q = o & 7;
#pragma unroll
        for (int kt = 0; kt < 8; ++kt) {
            const int k0 = K0 + kt * 32 + lg * 8;
#pragma unroll
            for (int p = 0; p < 4; ++p) {
                float e0 = Wg[((size_t)g * 2048 + 1024 + k0 + 2 * p) * 8 + q];
                float e1 = Wg[((size_t)g * 2048 + 1024 + k0 + 2 * p + 1) * 8 + q];
                wf[ro][kt].u[p] = pack_bf2(e0, e1);
            }
        }
    }
    // --- phase-2 weights: Wp[.][.][h] for h = 4*tid + hh (f32) ---
    float wpv[4][32], bpv[4][4];
#pragma unroll
    for (int hh = 0; hh < 4; ++hh) {
#pragma unroll
        for (int j = 0; j < 32; ++j)
            wpv[hh][j] = Wp[(size_t)j * H_DIM + 4 * tid + hh];
#pragma unroll
        for (int gg = 0; gg < 4; ++gg)
            bpv[hh][gg] = bp[gg * H_DIM + 4 * tid + hh];
    }

    // stage gx[t][b][0..31] for all t
    for (int i = tid; i < T_LEN * 32; i += 256)
        gxl[i] = gx[((size_t)(i >> 5) * B_SZ + b) * 32 + (i & 31)];

    *(uint2*)&hsb[2 * tid] = (uint2){0u, 0u};  // h_{-1} = 0
    float cx0 = 0.f, cx1 = 0.f, cx2 = 0.f, cx3 = 0.f;
    __syncthreads();

    const f32x4 zf = (f32x4){0.f, 0.f, 0.f, 0.f};

    for (int t8 = 0; t8 < T_LEN / 8; ++t8) {
        uint2 hv8[8];
#pragma unroll
        for (int tt = 0; tt < 8; ++tt) {
            const int t = t8 * 8 + tt;

            // ---- phase 1: partial raw via MFMA, 4 independent accum chains ----
            f32x4 p0a = zf, p0b = zf, p1a = zf, p1b = zf;
#pragma unroll
            for (int kt = 0; kt < 8; kt += 2) {
                short8 bfA = *(const short8*)((const char*)hsb + 2 * K0 + 64 * kt + lg * 16);
                short8 bfB = *(const short8*)((const char*)hsb + 2 * K0 + 64 * (kt + 1) + lg * 16);
                p0a = __builtin_amdgcn_mfma_f32_16x16x32_bf16(wf[0][kt].s8, bfA, p0a, 0, 0, 0);
                p1a = __builtin_amdgcn_mfma_f32_16x16x32_bf16(wf[1][kt].s8, bfA, p1a, 0, 0, 0);
                p0b = __builtin_amdgcn_mfma_f32_16x16x32_bf16(wf[0][kt + 1].s8, bfB, p0b, 0, 0, 0);
                p1b = __builtin_amdgcn_mfma_f32_16x16x32_bf16(wf[1][kt + 1].s8, bfB, p1b, 0, 0, 0);
            }
            f32x4 p0 = p0a + p0b, p1 = p1a + p1b;
            // D cols identical; lane (l&15)==0 holds rows lg*4..lg*4+3 per frag
            if ((lane & 15) == 0) {
                *(f32x4*)&red[wv * 36 + 4 * lg] = p0;
                *(f32x4*)&red[wv * 36 + 16 + 4 * lg] = p1;
            }
            __syncthreads();                    // B1: red ready

            // ---- stage, replicated per wave: sum 4 partials + cos, shfl-broadcast ----
            float r = gxl[t * 32 + ol]
                    + red[0 * 36 + ol] + red[1 * 36 + ol]
                    + red[2 * 36 + ol] + red[3 * 36 + ol];
            const float qv = __cosf(r);         // <Z> = cos(raw + theta)
            float qa[32];
#pragma unroll
            for (int o = 0; o < 32; ++o) qa[o] = __shfl(qv, o, 64);

            // ---- phase 2: projection + gates, h = 4*tid + hh ----
            float hv[4];
#pragma unroll
            for (int hh = 0; hh < 4; ++hh) {
                float pj[4];
#pragma unroll
                for (int gg = 0; gg < 4; ++gg) {
                    float s = bpv[hh][gg];
#pragma unroll
                    for (int j = 0; j < 8; ++j)
                        s = fmaf(qa[gg * 8 + j], wpv[hh][gg * 8 + j], s);
                    pj[gg] = s;
                }
                const float f_ = sigmoid_f(pj[0]);
                const float i_ = sigmoid_f(pj[1]);
                const float g_ = tanh_f(pj[2]);
                const float o_ = sigmoid_f(pj[3]);
                float& cx = (hh == 0) ? cx0 : (hh == 1) ? cx1 : (hh == 2) ? cx2 : cx3;
                cx = f_ * cx + i_ * g_;
                hv[hh] = o_ * tanh_f(cx);
            }
            const uint2 hvp = (uint2){pack_bf2(hv[0], hv[1]), pack_bf2(hv[2], hv[3])};
            *(uint2*)&hsb[2 * tid] = hvp;       // bf16 h for next step's MFMA
            hv8[tt] = hvp;                      // static index (rule #20)
            __syncthreads();                    // B2: h ready
        }
        // flush 8 steps of hb: vmcnt(0) drain at the next barrier costs once/8
#pragma unroll
        for (int tt = 0; tt < 8; ++tt)
            ((uint2*)hb)[((size_t)(t8 * 8 + tt) * B_SZ + b) * 256 + tid] = hv8[tt];
    }
}

// ---------- K3: tag GEMM + fused log-softmax over batch ----------
// C(32768x1024) = Hb(bf16) x W_tag(bf16), then log_softmax over the batch axis.
// Tile: M=256 rows = ALL batch rows of one t (m0 = t*256), N=128 cols. Grid (128, 8),
// 512 thr = 8 waves in 4(M) x 2(N); 64x64 per wave (4x4 MFMA frags). The softmax
// reduction (over the 256 rows) lives entirely in this block: per-column max/sum via
// in-reg reduce + shfl_xor(16,32) + small LDS cross-wave combine. Writes acc - lse.
// b_tag omitted: constant along batch -> cancels exactly in log_softmax.
__global__ __launch_bounds__(512) void k_tag_gemm_lsm(const __hip_bfloat16* __restrict__ Hb,
                                                      const __hip_bfloat16* __restrict__ WtT,
                                                      float* __restrict__ out)
{
    __shared__ short As[256 * 32];   // 16 KB [row][k] bf16 (global_load_lds layout)
    __shared__ short Bs[128 * 32];   // 8 KB  [n][k]   bf16
    __shared__ float wred[8][64];    // per-wave col-max partials [nh*4+mw][col-local]
    __shared__ float wsum[8][64];    // per-wave col-expsum partials

    const int t = blockIdx.x, n0 = blockIdx.y * 128;
    const int m0 = t * 256;
    const int tid = threadIdx.x, lane = tid & 63, wid = tid >> 6;
    const int wm = (wid & 3) * 64, wn = (wid >> 2) * 64;
    const int mrow = lane & 15, quad = lane >> 4;
    const int nh = wid >> 2, mw = wid & 3;

    const short* Hs = (const short*)Hb;
    const short* Ws = (const short*)WtT;

    f32x4 acc[4][4];
#pragma unroll
    for (int mi = 0; mi < 4; ++mi)
#pragma unroll
        for (int ni = 0; ni < 4; ++ni)
            acc[mi][ni] = (f32x4){0.f, 0.f, 0.f, 0.f};

    for (int kt = 0; kt < 32; ++kt) {
        const int k0 = kt * 32;
        __syncthreads();   // protect LDS from previous iteration's readers
        // stage A (16 KB, 2 rounds) + B (8 KB, 1 round); 1 KB per wave-chunk
#pragma unroll
        for (int rd = 0; rd < 2; ++rd) {
            const int c = wid + rd * 8;                     // 0..15
            const int row = c * 16 + (lane >> 2);
            const int kc = (lane & 3) * 8;
            gload_lds16(&As[c * 512], &Hs[(size_t)(m0 + row) * H_DIM + k0 + kc]);
        }
        {
            const int c = wid;                              // 0..7
            const int row = c * 16 + (lane >> 2);
            const int kc = (lane & 3) * 8;
            gload_lds16(&Bs[c * 512], &Ws[(size_t)(n0 + row) * H_DIM + k0 + kc]);
        }
        __syncthreads();   // compiler drains vmcnt before barrier

        short8 afr[4], bfr[4];
#pragma unroll
        for (int mi = 0; mi < 4; ++mi)
            afr[mi] = *(const short8*)&As[(wm + mi * 16 + mrow) * 32 + quad * 8];
#pragma unroll
        for (int ni = 0; ni < 4; ++ni)
            bfr[ni] = *(const short8*)&Bs[(wn + ni * 16 + mrow) * 32 + quad * 8];
#pragma unroll
        for (int mi = 0; mi < 4; ++mi)
#pragma unroll
            for (int ni = 0; ni < 4; ++ni)
                acc[mi][ni] = __builtin_amdgcn_mfma_f32_16x16x32_bf16(
                    afr[mi], bfr[ni], acc[mi][ni], 0, 0, 0);
    }

    // ---- fused log-softmax epilogue over the 256 rows (batch axis) ----
    // D frag: row = quad*4 + r (+ mi*16 + wm), col = mrow (+ ni*16 + wn)
    float cmax[4];
#pragma unroll
    for (int ni = 0; ni < 4; ++ni) {
        float m = -1e30f;
#pragma unroll
        for (int mi = 0; mi < 4; ++mi)
#pragma unroll
            for (int r = 0; r < 4; ++r) m = fmaxf(m, acc[mi][ni][r]);
        m = fmaxf(m, __shfl_xor(m, 16, 64));    // reduce over quads (wave's 64 rows)
        m = fmaxf(m, __shfl_xor(m, 32, 64));
        cmax[ni] = m;
    }
    if (quad == 0) {
#pragma unroll
        for (int ni = 0; ni < 4; ++ni) wred[nh * 4 + mw][ni * 16 + mrow] = cmax[ni];
    }
    __syncthreads();
#pragma unroll
    for (int ni = 0; ni < 4; ++ni) {
        float m = wred[nh * 4 + 0][ni * 16 + mrow];
        m = fmaxf(m, wred[nh * 4 + 1][ni * 16 + mrow]);
        m = fmaxf(m, wred[nh * 4 + 2][ni * 16 + mrow]);
        m = fmaxf(m, wred[nh * 4 + 3][ni * 16 + mrow]);
        cmax[ni] = m;
    }
    float lse[4];
#pragma unroll
    for (int ni = 0; ni < 4; ++ni) {
        float s = 0.f;
#pragma unroll
        for (int mi = 0; mi < 4; ++mi)
#pragma unroll
            for (int r = 0; r < 4; ++r) s += __expf(acc[mi][ni][r] - cmax[ni]);
        s += __shfl_xor(s, 16, 64);
        s += __shfl_xor(s, 32, 64);
        lse[ni] = s;                            // wave-local sum for now
    }
    if (quad == 0) {
#pragma unroll
        for (int ni = 0; ni < 4; ++ni) wsum[nh * 4 + mw][ni * 16 + mrow] = lse[ni];
    }
    __syncthreads();
#pragma unroll
    for (int ni = 0; ni < 4; ++ni) {
        const float s = wsum[nh * 4 + 0][ni * 16 + mrow]
                      + wsum[nh * 4 + 1][ni * 16 + mrow]
                      + wsum[nh * 4 + 2][ni * 16 + mrow]
                      + wsum[nh * 4 + 3][ni * 16 + mrow];
        lse[ni] = cmax[ni] + __logf(s);
    }
#pragma unroll
    for (int mi = 0; mi < 4; ++mi)
#pragma unroll
        for (int ni = 0; ni < 4; ++ni)
#pragma unroll
            for (int r = 0; r < 4; ++r) {
                const int grow = m0 + wm + mi * 16 + quad * 4 + r;
                const int gcol = n0 + wn + ni * 16 + mrow;
                out[(size_t)grow * TAGS + gcol] = acc[mi][ni][r] - lse[ni];
            }
}

extern "C" void kernel_launch(void* const* d_in, const int* in_sizes, int n_in,
                              void* d_out, int out_size, void* d_ws, size_t ws_size,
                              hipStream_t stream) {
    (void)in_sizes; (void)n_in; (void)out_size; (void)ws_size;
    const int*   sent  = (const int*)d_in[0];
    const float* emb   = (const float*)d_in[1];
    const float* Wg    = (const float*)d_in[2];
    const float* bg    = (const float*)d_in[3];
    const float* theta = (const float*)d_in[4];
    const float* Wp    = (const float*)d_in[5];
    const float* bp    = (const float*)d_in[6];
    const float* Wt    = (const float*)d_in[7];
    // d_in[8] = b_tag: constant along the softmax (batch) axis -> cancels exactly.
    float* out = (float*)d_out;

    __hip_bfloat16* hb  = (__hip_bfloat16*)d_ws;                                     // 64 MB: lstm_out bf16
    __hip_bfloat16* WtT = (__hip_bfloat16*)((char*)d_ws + (size_t)64 * 1024 * 1024); // 2 MB: W_tag^T bf16
    // gx scratch (4 MB) lives in the FIRST part of the out buffer: it is consumed by
    // k_qlstm before the GEMM overwrites out. No extra workspace needed.
    float* gx = (float*)d_out;

    k_wt_transpose<<<dim3(32, 32), 256, 0, stream>>>(Wt, WtT);
    k_gx<<<dim3((T_LEN * B_SZ) / GXB_ROWS), 256, 0, stream>>>(sent, emb, Wg, bg, theta, gx);
    k_qlstm<<<dim3(B_SZ), 256, 0, stream>>>(gx, Wg, Wp, bp, hb);
    k_tag_gemm_lsm<<<dim3(T_LEN, TAGS / 128), 512, 0, stream>>>(hb, WtT, out);
}

// Round 6
// 564.651 us; speedup vs baseline: 1.3929x; 1.0171x over previous
//
#include <hip/hip_runtime.h>
#include <hip/hip_bf16.h>
#include <stdint.h>

// Problem dims (fixed by reference)
#define T_LEN 128
#define B_SZ  256
#define D_IN  1024
#define H_DIM 1024
#define NQ    8
#define VOCAB 32000
#define TAGS  1024

typedef __attribute__((ext_vector_type(8))) short short8;   // 8 bf16 (4 VGPRs)
typedef __attribute__((ext_vector_type(4))) float f32x4;

// ---------- helpers ----------
__device__ __forceinline__ unsigned short f2bf_bits(float x) {
    __hip_bfloat16 h = __float2bfloat16(x);
    unsigned short u; __builtin_memcpy(&u, &h, 2); return u;
}
__device__ __forceinline__ uint32_t pack_bf2(float a, float b) {
    return (uint32_t)f2bf_bits(a) | ((uint32_t)f2bf_bits(b) << 16);
}
__device__ __forceinline__ float sigmoid_f(float x) {
    return 1.f / (1.f + __expf(-x));
}
__device__ __forceinline__ float tanh_f(float x) {
    // 1 - 2/(e^{2x}+1); saturates correctly at +/-1 (inf-safe)
    return 1.f - 2.f / (__expf(2.f * x) + 1.f);
}
__device__ __forceinline__ void gload_lds16(void* lds_base, const void* gptr) {
    __builtin_amdgcn_global_load_lds(
        (__attribute__((address_space(1))) const void*)gptr,
        (__attribute__((address_space(3))) void*)lds_base,
        16, 0, 0);
}

// ---------- K0: W_tag (K x N fp32) -> WtT (N x K bf16) ----------
__global__ __launch_bounds__(256) void k_wt_transpose(const float* __restrict__ W,
                                                      __hip_bfloat16* __restrict__ WtT) {
    __shared__ float tile[32][33];
    const int kb = blockIdx.x * 32, nb = blockIdx.y * 32;
    const int r = threadIdx.x >> 5, c = threadIdx.x & 31;
#pragma unroll
    for (int i = 0; i < 4; ++i)
        tile[r + 8 * i][c] = W[(size_t)(kb + r + 8 * i) * TAGS + nb + c];
    __syncthreads();
#pragma unroll
    for (int i = 0; i < 4; ++i)
        WtT[(size_t)(nb + r + 8 * i) * H_DIM + kb + c] = __float2bfloat16(tile[c][r + 8 * i]);
}

// ---------- K1: gx[r][o] = emb[sent[r]] . Wg_x[:,o] + bg[o] + theta[o] ----------
#define GXB_ROWS 32
__global__ __launch_bounds__(256, 2) void k_gx(
    const int* __restrict__ sent, const float* __restrict__ emb,
    const float* __restrict__ Wg, const float* __restrict__ bg,
    const float* __restrict__ theta, float* __restrict__ gx)
{
    __shared__ float xs[2][1024];
    const int tid = threadIdx.x, lane = tid & 63, wv = tid >> 6;
    const int ol = lane & 7, s = lane >> 3;         // output-local, slice
    const int o = wv * 8 + ol;                      // g = wv, q = ol

    float wk[128];
#pragma unroll
    for (int k = 0; k < 32; ++k)
#pragma unroll
        for (int e = 0; e < 4; ++e) {
            const int c = (s + 8 * k) * 4 + e;      // x part: rows [0,1024)
            wk[4 * k + e] = Wg[((size_t)wv * 2048 + c) * 8 + ol];
        }
    const float bt = bg[o] + theta[o];

    const int rbase = blockIdx.x * GXB_ROWS;
    const float4* emb4 = (const float4*)emb;
    float4 xn = emb4[(size_t)sent[rbase] * 256 + tid];
    *(float4*)&xs[0][4 * tid] = xn;
    __syncthreads();

    int cur = 0;
    for (int i8 = 0; i8 < GXB_ROWS / 8; ++i8) {
        float gacc[8];
#pragma unroll
        for (int ii = 0; ii < 8; ++ii) {
            const int i = i8 * 8 + ii;
            const bool havenext = (i + 1 < GXB_ROWS);
            if (havenext)
                xn = emb4[(size_t)sent[rbase + i + 1] * 256 + tid];   // prefetch

            const float4* x4 = (const float4*)xs[cur];
            float a0 = 0.f, a1 = 0.f, a2 = 0.f, a3 = 0.f;
#pragma unroll
            for (int k = 0; k < 32; ++k) {
                float4 v = x4[s + 8 * k];
                a0 = fmaf(wk[4 * k + 0], v.x, a0);
                a1 = fmaf(wk[4 * k + 1], v.y, a1);
                a2 = fmaf(wk[4 * k + 2], v.z, a2);
                a3 = fmaf(wk[4 * k + 3], v.w, a3);
            }
            float a = (a0 + a1) + (a2 + a3);
#pragma unroll
            for (int d = 8; d < 64; d <<= 1) a += __shfl_xor(a, d, 64);
            gacc[ii] = a + bt;

            if (havenext)
                *(float4*)&xs[cur ^ 1][4 * tid] = xn;   // other buffer: pre-barrier OK
            __syncthreads();
            cur ^= 1;
        }
        if (lane < 8) {
#pragma unroll
            for (int ii = 0; ii < 8; ++ii)
                gx[(size_t)(rbase + i8 * 8 + ii) * 32 + wv * 8 + lane] = gacc[ii];
        }
    }
}

// ---------- K2: recurrent QLSTM v6. one block (512 thr / 8 waves) per batch ----------
// v4's occupancy (8 waves = 2/SIMD, latency-hiding) + v5's replicated stage (no
// serial section) = 2 barriers/step.
//  ph1: wave wv owns k-slice [128wv,128wv+128): 4 broadcast ds_read_b128 of bf16 h +
//       8 mfma_16x16x32_bf16 (A-frags 32 VGPR, 4 indep chains). Partials ->
//       red[8][36] (lanes l&15==0). B1.
//  stage (replicated in every wave): r = gx + sum of 8 partials (broadcast LDS
//       reads), cos, 32x __shfl broadcast -> qa[32]. No barrier, no serial section.
//  ph2: 2 h/thread (v4 math), h -> packed bf16 in LDS. B2.
//  hb stores batched x8 in static regs -> vmcnt(0) drain once per 8 steps.
__global__ __launch_bounds__(512, 1) void k_qlstm(
    const float* __restrict__ gx, const float* __restrict__ Wg,
    const float* __restrict__ Wp, const float* __restrict__ bp,
    __hip_bfloat16* __restrict__ hb)
{
    __shared__ uint32_t hsb[512];              // h as packed bf16 pairs (2 KB)
    __shared__ float red[8 * 36];              // per-wave partials, stride 36
    __shared__ float gxl[T_LEN * 32];          // 16 KB: this block's gx slice

    const int tid = threadIdx.x, lane = tid & 63, wv = tid >> 6;
    const int b = blockIdx.x;
    const int lg = lane >> 4;                  // k-octet group 0..3
    const int K0 = wv * 128;                   // this wave's h-slice base
    const int ol = lane & 31;                  // output index for stage

    // --- phase-1 weights as MFMA A-frags: lane l holds A[l&15][lg*8+j] ---
    union { short8 s8; uint32_t u[4]; } wf[2][4];
#pragma unroll
    for (int ro = 0; ro < 2; ++ro) {
        const int o = ro * 16 + (lane & 15);
        const int g = o >> 3, q = o & 7;
#pragma unroll
        for (int kt = 0; kt < 4; ++kt) {
            const int k0 = K0 + kt * 32 + lg * 8;
#pragma unroll
            for (int p = 0; p < 4; ++p) {
                float e0 = Wg[((size_t)g * 2048 + 1024 + k0 + 2 * p) * 8 + q];
                float e1 = Wg[((size_t)g * 2048 + 1024 + k0 + 2 * p + 1) * 8 + q];
                wf[ro][kt].u[p] = pack_bf2(e0, e1);
            }
        }
    }
    // --- phase-2 weights: Wp[.][.][h] for h = 2*tid, 2*tid+1 (f32) ---
    float wpA[32], wpB[32];
#pragma unroll
    for (int j = 0; j < 32; ++j) {
        wpA[j] = Wp[(size_t)j * H_DIM + 2 * tid];
        wpB[j] = Wp[(size_t)j * H_DIM + 2 * tid + 1];
    }
    float bpA[4], bpB[4];
#pragma unroll
    for (int gg = 0; gg < 4; ++gg) {
        bpA[gg] = bp[gg * H_DIM + 2 * tid];
        bpB[gg] = bp[gg * H_DIM + 2 * tid + 1];
    }

    // stage gx[t][b][0..31] for all t
    for (int i = tid; i < T_LEN * 32; i += 512)
        gxl[i] = gx[((size_t)(i >> 5) * B_SZ + b) * 32 + (i & 31)];

    hsb[tid] = 0u;                             // h_{-1} = 0
    float cx0 = 0.f, cx1 = 0.f;
    __syncthreads();

    uint32_t* hb32 = (uint32_t*)hb;
    const f32x4 zf = (f32x4){0.f, 0.f, 0.f, 0.f};

    for (int t8 = 0; t8 < T_LEN / 8; ++t8) {
        uint32_t hv8[8];
#pragma unroll
        for (int tt = 0; tt < 8; ++tt) {
            const int t = t8 * 8 + tt;

            // ---- phase 1: partial raw via MFMA, 4 independent accum chains ----
            f32x4 p0a = zf, p0b = zf, p1a = zf, p1b = zf;
#pragma unroll
            for (int kt = 0; kt < 4; kt += 2) {
                short8 bfA = *(const short8*)((const char*)hsb + 2 * K0 + 64 * kt + lg * 16);
                short8 bfB = *(const short8*)((const char*)hsb + 2 * K0 + 64 * (kt + 1) + lg * 16);
                p0a = __builtin_amdgcn_mfma_f32_16x16x32_bf16(wf[0][kt].s8, bfA, p0a, 0, 0, 0);
                p1a = __builtin_amdgcn_mfma_f32_16x16x32_bf16(wf[1][kt].s8, bfA, p1a, 0, 0, 0);
                p0b = __builtin_amdgcn_mfma_f32_16x16x32_bf16(wf[0][kt + 1].s8, bfB, p0b, 0, 0, 0);
                p1b = __builtin_amdgcn_mfma_f32_16x16x32_bf16(wf[1][kt + 1].s8, bfB, p1b, 0, 0, 0);
            }
            f32x4 p0 = p0a + p0b, p1 = p1a + p1b;
            // D cols identical; lane (l&15)==0 holds rows lg*4..lg*4+3 per frag
            if ((lane & 15) == 0) {
                *(f32x4*)&red[wv * 36 + 4 * lg] = p0;
                *(f32x4*)&red[wv * 36 + 16 + 4 * lg] = p1;
            }
            __syncthreads();                    // B1: red ready

            // ---- stage, replicated per wave: sum 8 partials + cos, shfl-broadcast ----
            float r = gxl[t * 32 + ol];
#pragma unroll
            for (int w = 0; w < 8; ++w) r += red[w * 36 + ol];
            const float qv = __cosf(r);         // <Z> = cos(raw + theta)
            float qa[32];
#pragma unroll
            for (int o = 0; o < 32; ++o) qa[o] = __shfl(qv, o, 64);

            // ---- phase 2: projection + gates, h = 2*tid, 2*tid+1 ----
            float pjA[4], pjB[4];
#pragma unroll
            for (int gg = 0; gg < 4; ++gg) {
                float sA = bpA[gg], sB = bpB[gg];
#pragma unroll
                for (int j = 0; j < 8; ++j) {
                    sA = fmaf(qa[gg * 8 + j], wpA[gg * 8 + j], sA);
                    sB = fmaf(qa[gg * 8 + j], wpB[gg * 8 + j], sB);
                }
                pjA[gg] = sA; pjB[gg] = sB;
            }
            const float fA = sigmoid_f(pjA[0]), iA = sigmoid_f(pjA[1]);
            const float gA = tanh_f(pjA[2]),   oA = sigmoid_f(pjA[3]);
            const float fB = sigmoid_f(pjB[0]), iB = sigmoid_f(pjB[1]);
            const float gB = tanh_f(pjB[2]),   oB = sigmoid_f(pjB[3]);
            cx0 = fA * cx0 + iA * gA;
            cx1 = fB * cx1 + iB * gB;
            const float hv0 = oA * tanh_f(cx0);
            const float hv1 = oB * tanh_f(cx1);
            const uint32_t hvp = pack_bf2(hv0, hv1);
            hsb[tid] = hvp;                     // bf16 h for next step's MFMA
            hv8[tt] = hvp;                      // static index (rule #20)
            __syncthreads();                    // B2: h ready
        }
        // flush 8 steps of hb: vmcnt(0) drain at the next barrier costs once/8
#pragma unroll
        for (int tt = 0; tt < 8; ++tt)
            hb32[((size_t)(t8 * 8 + tt) * B_SZ + b) * 512 + tid] = hv8[tt];
    }
}

// ---------- K3: tag GEMM + fused log-softmax over batch ----------
// C(32768x1024) = Hb(bf16) x W_tag(bf16), then log_softmax over the batch axis.
// Tile: M=256 rows = ALL batch rows of one t (m0 = t*256), N=128 cols. Grid (128, 8),
// 512 thr = 8 waves in 4(M) x 2(N); 64x64 per wave (4x4 MFMA frags). The softmax
// reduction (over the 256 rows) lives entirely in this block. Writes acc - lse.
// b_tag omitted: constant along batch -> cancels exactly in log_softmax.
__global__ __launch_bounds__(512) void k_tag_gemm_lsm(const __hip_bfloat16* __restrict__ Hb,
                                                      const __hip_bfloat16* __restrict__ WtT,
                                                      float* __restrict__ out)
{
    __shared__ short As[256 * 32];   // 16 KB [row][k] bf16 (global_load_lds layout)
    __shared__ short Bs[128 * 32];   // 8 KB  [n][k]   bf16
    __shared__ float wred[8][64];    // per-wave col-max partials [nh*4+mw][col-local]
    __shared__ float wsum[8][64];    // per-wave col-expsum partials

    const int t = blockIdx.x, n0 = blockIdx.y * 128;
    const int m0 = t * 256;
    const int tid = threadIdx.x, lane = tid & 63, wid = tid >> 6;
    const int wm = (wid & 3) * 64, wn = (wid >> 2) * 64;
    const int mrow = lane & 15, quad = lane >> 4;
    const int nh = wid >> 2, mw = wid & 3;

    const short* Hs = (const short*)Hb;
    const short* Ws = (const short*)WtT;

    f32x4 acc[4][4];
#pragma unroll
    for (int mi = 0; mi < 4; ++mi)
#pragma unroll
        for (int ni = 0; ni < 4; ++ni)
            acc[mi][ni] = (f32x4){0.f, 0.f, 0.f, 0.f};

    for (int kt = 0; kt < 32; ++kt) {
        const int k0 = kt * 32;
        __syncthreads();   // protect LDS from previous iteration's readers
        // stage A (16 KB, 2 rounds) + B (8 KB, 1 round); 1 KB per wave-chunk
#pragma unroll
        for (int rd = 0; rd < 2; ++rd) {
            const int c = wid + rd * 8;                     // 0..15
            const int row = c * 16 + (lane >> 2);
            const int kc = (lane & 3) * 8;
            gload_lds16(&As[c * 512], &Hs[(size_t)(m0 + row) * H_DIM + k0 + kc]);
        }
        {
            const int c = wid;                              // 0..7
            const int row = c * 16 + (lane >> 2);
            const int kc = (lane & 3) * 8;
            gload_lds16(&Bs[c * 512], &Ws[(size_t)(n0 + row) * H_DIM + k0 + kc]);
        }
        __syncthreads();   // compiler drains vmcnt before barrier

        short8 afr[4], bfr[4];
#pragma unroll
        for (int mi = 0; mi < 4; ++mi)
            afr[mi] = *(const short8*)&As[(wm + mi * 16 + mrow) * 32 + quad * 8];
#pragma unroll
        for (int ni = 0; ni < 4; ++ni)
            bfr[ni] = *(const short8*)&Bs[(wn + ni * 16 + mrow) * 32 + quad * 8];
#pragma unroll
        for (int mi = 0; mi < 4; ++mi)
#pragma unroll
            for (int ni = 0; ni < 4; ++ni)
                acc[mi][ni] = __builtin_amdgcn_mfma_f32_16x16x32_bf16(
                    afr[mi], bfr[ni], acc[mi][ni], 0, 0, 0);
    }

    // ---- fused log-softmax epilogue over the 256 rows (batch axis) ----
    // D frag: row = quad*4 + r (+ mi*16 + wm), col = mrow (+ ni*16 + wn)
    float cmax[4];
#pragma unroll
    for (int ni = 0; ni < 4; ++ni) {
        float m = -1e30f;
#pragma unroll
        for (int mi = 0; mi < 4; ++mi)
#pragma unroll
            for (int r = 0; r < 4; ++r) m = fmaxf(m, acc[mi][ni][r]);
        m = fmaxf(m, __shfl_xor(m, 16, 64));    // reduce over quads (wave's 64 rows)
        m = fmaxf(m, __shfl_xor(m, 32, 64));
        cmax[ni] = m;
    }
    if (quad == 0) {
#pragma unroll
        for (int ni = 0; ni < 4; ++ni) wred[nh * 4 + mw][ni * 16 + mrow] = cmax[ni];
    }
    __syncthreads();
#pragma unroll
    for (int ni = 0; ni < 4; ++ni) {
        float m = wred[nh * 4 + 0][ni * 16 + mrow];
        m = fmaxf(m, wred[nh * 4 + 1][ni * 16 + mrow]);
        m = fmaxf(m, wred[nh * 4 + 2][ni * 16 + mrow]);
        m = fmaxf(m, wred[nh * 4 + 3][ni * 16 + mrow]);
        cmax[ni] = m;
    }
    float lse[4];
#pragma unroll
    for (int ni = 0; ni < 4; ++ni) {
        float s = 0.f;
#pragma unroll
        for (int mi = 0; mi < 4; ++mi)
#pragma unroll
            for (int r = 0; r < 4; ++r) s += __expf(acc[mi][ni][r] - cmax[ni]);
        s += __shfl_xor(s, 16, 64);
        s += __shfl_xor(s, 32, 64);
        lse[ni] = s;                            // wave-local sum for now
    }
    if (quad == 0) {
#pragma unroll
        for (int ni = 0; ni < 4; ++ni) wsum[nh * 4 + mw][ni * 16 + mrow] = lse[ni];
    }
    __syncthreads();
#pragma unroll
    for (int ni = 0; ni < 4; ++ni) {
        const float s = wsum[nh * 4 + 0][ni * 16 + mrow]
                      + wsum[nh * 4 + 1][ni * 16 + mrow]
                      + wsum[nh * 4 + 2][ni * 16 + mrow]
                      + wsum[nh * 4 + 3][ni * 16 + mrow];
        lse[ni] = cmax[ni] + __logf(s);
    }
#pragma unroll
    for (int mi = 0; mi < 4; ++mi)
#pragma unroll
        for (int ni = 0; ni < 4; ++ni)
#pragma unroll
            for (int r = 0; r < 4; ++r) {
                const int grow = m0 + wm + mi * 16 + quad * 4 + r;
                const int gcol = n0 + wn + ni * 16 + mrow;
                out[(size_t)grow * TAGS + gcol] = acc[mi][ni][r] - lse[ni];
            }
}

extern "C" void kernel_launch(void* const* d_in, const int* in_sizes, int n_in,
                              void* d_out, int out_size, void* d_ws, size_t ws_size,
                              hipStream_t stream) {
    (void)in_sizes; (void)n_in; (void)out_size; (void)ws_size;
    const int*   sent  = (const int*)d_in[0];
    const float* emb   = (const float*)d_in[1];
    const float* Wg    = (const float*)d_in[2];
    const float* bg    = (const float*)d_in[3];
    const float* theta = (const float*)d_in[4];
    const float* Wp    = (const float*)d_in[5];
    const float* bp    = (const float*)d_in[6];
    const float* Wt    = (const float*)d_in[7];
    // d_in[8] = b_tag: constant along the softmax (batch) axis -> cancels exactly.
    float* out = (float*)d_out;

    __hip_bfloat16* hb  = (__hip_bfloat16*)d_ws;                                     // 64 MB: lstm_out bf16
    __hip_bfloat16* WtT = (__hip_bfloat16*)((char*)d_ws + (size_t)64 * 1024 * 1024); // 2 MB: W_tag^T bf16
    // gx scratch (4 MB) lives in the FIRST part of the out buffer: it is consumed by
    // k_qlstm before the GEMM overwrites out. No extra workspace needed.
    float* gx = (float*)d_out;

    k_wt_transpose<<<dim3(32, 32), 256, 0, stream>>>(Wt, WtT);
    k_gx<<<dim3((T_LEN * B_SZ) / GXB_ROWS), 256, 0, stream>>>(sent, emb, Wg, bg, theta, gx);
    k_qlstm<<<dim3(B_SZ), 512, 0, stream>>>(gx, Wg, Wp, bp, hb);
    k_tag_gemm_lsm<<<dim3(T_LEN, TAGS / 128), 512, 0, stream>>>(hb, WtT, out);
}